// Round 8
// baseline (1565.356 us; speedup 1.0000x reference)
//
#include <hip/hip_runtime.h>
#include <hip/hip_bf16.h>
#include <stdint.h>

// Problem constants (fixed by the reference)
#define HD      4096            // K (hidden)
#define MROWS   8192            // B*S
#define NQ      4096
#define NKV     1024
#define NTOT    6144            // NQ + 2*NKV
#define RMS_EPS 1e-6f

typedef __attribute__((ext_vector_type(8))) short bf16x8;
typedef __attribute__((ext_vector_type(16))) float f32x16;

static __device__ __forceinline__ unsigned short f2bf(float f) {
  union { float f; unsigned u; } a; a.f = f;
  unsigned r = a.u + 0x7FFFu + ((a.u >> 16) & 1u);   // RNE
  return (unsigned short)(r >> 16);
}

// ---------------- RMSNorm + cast to bf16 ----------------
__global__ __launch_bounds__(256) void rmsnorm_cast_kernel(
    const float* __restrict__ x, const float* __restrict__ gamma,
    unsigned short* __restrict__ xn) {
  const int row = blockIdx.x;                 // 8192 rows
  const float4* xr = (const float4*)(x + (size_t)row * HD);
  const float4* g4 = (const float4*)gamma;
  const int t = threadIdx.x;                  // 256 threads
  float4 v[4];
  float ss = 0.f;
#pragma unroll
  for (int i = 0; i < 4; ++i) {
    v[i] = xr[t + i * 256];
    ss += v[i].x * v[i].x + v[i].y * v[i].y + v[i].z * v[i].z + v[i].w * v[i].w;
  }
#pragma unroll
  for (int o = 32; o > 0; o >>= 1) ss += __shfl_xor(ss, o, 64);
  __shared__ float red[4];
  if ((t & 63) == 0) red[t >> 6] = ss;
  __syncthreads();
  const float tot = red[0] + red[1] + red[2] + red[3];
  const float rstd = rsqrtf(tot * (1.f / HD) + RMS_EPS);
  ushort4* xo = (ushort4*)(xn + (size_t)row * HD);
#pragma unroll
  for (int i = 0; i < 4; ++i) {
    const float4 g = g4[t + i * 256];
    ushort4 o;
    o.x = f2bf(v[i].x * rstd * g.x);
    o.y = f2bf(v[i].y * rstd * g.y);
    o.z = f2bf(v[i].z * rstd * g.z);
    o.w = f2bf(v[i].w * rstd * g.w);
    xo[t + i * 256] = o;
  }
}

// ---------------- Transpose + cast W[K][Nw] f32 -> Wt[Nw][K] bf16 ----------------
__global__ __launch_bounds__(256) void transpose_cast_kernel(
    const float* __restrict__ w, unsigned short* __restrict__ wt, int Nw) {
  __shared__ float tile[32][33];
  const int kt = blockIdx.y;                  // K/32
  const int nb = blockIdx.x;                  // Nw/32
  const int t = threadIdx.x;
  const int r = t >> 3, c4 = t & 7;
  const float4 vin = *(const float4*)&w[(size_t)(kt * 32 + r) * Nw + nb * 32 + c4 * 4];
  tile[r][c4 * 4 + 0] = vin.x;
  tile[r][c4 * 4 + 1] = vin.y;
  tile[r][c4 * 4 + 2] = vin.z;
  tile[r][c4 * 4 + 3] = vin.w;
  __syncthreads();
  ushort4 o;
  o.x = f2bf(tile[c4 * 4 + 0][r]);
  o.y = f2bf(tile[c4 * 4 + 1][r]);
  o.z = f2bf(tile[c4 * 4 + 2][r]);
  o.w = f2bf(tile[c4 * 4 + 3][r]);
  *(ushort4*)&wt[(size_t)(nb * 32 + r) * HD + kt * 32 + c4 * 4] = o;
}

// ---- 256x256 read-ahead-pipelined bf16 GEMM, 32x32x16 ----
// C[M,N] = A[M,K] * Bt[N,K]^T ; M=8192, N=6144, K=4096. BK=64, 512 thr.
//
// Per-tile quadrant order: p0:(A0,B0) p1:(A0,B1) p2:(A1,B1) p3:(A1,B0).
// Reads are DECOUPLED from their consuming phase (every operand read >=2
// phases before first use -> MFMA never lgkm-stalls; reads overlap MFMA):
//   T.p0: RD A1(T)      (a1; last use of old a1 was T-1.p3)
//   T.p2: RD A0(T+1)    (a0; last use T.p1)
//   T.p3: RD B1(T+1), B0(T+1)->bank (T+1)&1  (b1r last use T.p2; b0r banked)
// Stages during T (tile T+2 -> buf(T&1)): p0:A0 p1:B0 p2:B1 p3:A1.
//   Overwrite gaps (read-phase -> stage-phase, single-barrier rule >=2):
//   A0 T-1.p2->T.p0 (2) B0 T-1.p3->T.p1 (2) B1 T-1.p3->T.p2 (3) A1 T.p0->T.p3 (3)
// VM ledger (VM at phase start, before RD; 2 loads/STG):
//   VM6@p0: outstanding 10 -> drains {T-2.A1, T-1.A0} just in time for
//           T.p0's a1 read and T.p2's a0 read.
//   VM6@p2: outstanding 10 -> drains {T-1.B0, T-1.B1} for T.p3's reads.
//   Never 0 in main loop; VM0 once before epilogue.

static __device__ __forceinline__ void gload_lds16(const unsigned short* g,
                                                   unsigned short* l) {
  __builtin_amdgcn_global_load_lds(
      (const __attribute__((address_space(1))) void*)g,
      (__attribute__((address_space(3))) void*)l, 16, 0, 0);
}

#define VM6 asm volatile("s_waitcnt vmcnt(6)" ::: "memory")
#define VM8 asm volatile("s_waitcnt vmcnt(8)" ::: "memory")
#define VM0 asm volatile("s_waitcnt vmcnt(0)" ::: "memory")
#define BAR __builtin_amdgcn_s_barrier()

// ds-read 8 A fragments (2 m-blocks x 4 ks) of row-half HA into DST
#define RD_A(DST, BUF, HA)                                                     \
  do {                                                                         \
    const char* Ah = (const char*)&lds[0][BUF][HA][0];                         \
    _Pragma("unroll") for (int mi = 0; mi < 2; ++mi)                           \
      _Pragma("unroll") for (int k = 0; k < 4; ++k)                            \
        DST[mi][k] = *(const bf16x8*)(Ah + (wr * 64 + mi * 32 + r32) * 128 +   \
                                      (((k * 2 + hi) ^ swx) << 4));            \
  } while (0)

// ds-read 4 B fragments (4 ks) of col-half HB into DST
#define RD_B(DST, BUF, HB)                                                     \
  do {                                                                         \
    const char* Bh = (const char*)&lds[1][BUF][HB][0];                         \
    _Pragma("unroll") for (int k = 0; k < 4; ++k)                              \
      DST[k] = *(const bf16x8*)(Bh + (wc * 32 + r32) * 128 +                   \
                                (((k * 2 + hi) ^ swx) << 4));                  \
  } while (0)

// 8 MFMA: acc[I0][J], acc[I1][J] over K=64 with A regs AR, B regs BR
#define MM8(I0, I1, J, AR, BR)                                                 \
  do {                                                                         \
    __builtin_amdgcn_s_setprio(1);                                             \
    _Pragma("unroll") for (int k = 0; k < 4; ++k) {                            \
      acc[I0][J] = __builtin_amdgcn_mfma_f32_32x32x16_bf16(                    \
          AR[0][k], BR[k], acc[I0][J], 0, 0, 0);                               \
      acc[I1][J] = __builtin_amdgcn_mfma_f32_32x32x16_bf16(                    \
          AR[1][k], BR[k], acc[I1][J], 0, 0, 0);                               \
    }                                                                          \
    __builtin_amdgcn_s_setprio(0);                                             \
  } while (0)

// One K-tile: BUF = T&1 (compute buf), NBUF = (T+1)&1, BB = T&1 (b0 bank),
// NB = (T+1)&1, KO = clamped k-offset of tile T+2 (elements).
#define TILE(BUF, NBUF, BB, NB, KO)                                            \
  do {                                                                         \
    /* p0 */                                                                   \
    VM6; RD_A(a1, BUF, 1); STG(Ab0 + (KO), &lds[0][BUF][0][0]); BAR;           \
    MM8(0, 1, 0, a0, b0r[BB]);                                                 \
    /* p1 */                                                                   \
    STG(Bb0 + (KO), &lds[1][BUF][0][0]); BAR;                                  \
    MM8(0, 1, 1, a0, b1r);                                                     \
    /* p2 */                                                                   \
    VM6; RD_A(a0, NBUF, 0); STG(Bb1 + (KO), &lds[1][BUF][1][0]); BAR;          \
    MM8(2, 3, 1, a1, b1r);                                                     \
    /* p3 */                                                                   \
    RD_B(b1r, NBUF, 1); RD_B(b0r[NB], NBUF, 0);                                \
    STG(Ab1 + (KO), &lds[0][BUF][1][0]); BAR;                                  \
    MM8(2, 3, 0, a1, b0r[BB]);                                                 \
  } while (0)

__global__ __launch_bounds__(512, 2) void gemm_qkv_kernel(
    const unsigned short* __restrict__ A,    // [MROWS][HD] bf16 (xn)
    const unsigned short* __restrict__ Bt,   // [NTOT][HD] bf16 (w^T)
    float* __restrict__ out) {
  // [mat A/B][buf][row-half][128 rows x 64 k] bf16 = 128 KiB total
  __shared__ unsigned short lds[2][2][2][8192] __attribute__((aligned(16)));

  // XCD-rectangular swizzle: grid 32mt x 24nt = 768 blocks, XCD = bid&7.
  const int bid = blockIdx.x;
  const int xcd = bid & 7;
  const int idx = bid >> 3;                  // 0..95
  const int sr  = idx >> 5;                  // sub-round 0..2
  const int i32 = idx & 31;
  const int mt  = (xcd >> 1) * 8 + (i32 >> 2);
  const int nt  = (xcd & 1) * 12 + sr * 4 + (i32 & 3);
  const int m0 = mt * 256, n0 = nt * 256;

  const int tid = threadIdx.x;
  const int w = tid >> 6, lane = tid & 63;
  const int wr = w >> 2, wc = w & 3;         // 2 x 4 waves, each 128x64 out
  const int r32 = lane & 31, hi = lane >> 5; // 32x32 fragment coords
  const int swx = (r32 >> 1) & 7;            // bank swizzle field

  // staging: linear LDS dest, inverse-swizzled global source (rule #21)
  const int wslot = w * 512;                 // wave-uniform LDS element base
  const int r3 = tid >> 3;                   // row 0..63 within pass
  const int scolb = (((tid & 7) ^ ((r3 >> 1) & 7))) << 4;
  const size_t so0 = (size_t)r3 * HD + (scolb >> 1);
  const size_t so1 = so0 + (size_t)64 * HD;

  const unsigned short* const Ab0 = A + (size_t)m0 * HD;
  const unsigned short* const Ab1 = Ab0 + (size_t)128 * HD;
  const unsigned short* const Bb0 = Bt + (size_t)n0 * HD;
  const unsigned short* const Bb1 = Bb0 + (size_t)128 * HD;

  auto STG = [&](const unsigned short* g, unsigned short* l) {
    gload_lds16(g + so0, l + wslot);
    gload_lds16(g + so1, l + 4096 + wslot);
  };

  f32x16 acc[4][2];
#pragma unroll
  for (int i = 0; i < 4; ++i)
#pragma unroll
    for (int j = 0; j < 2; ++j) acc[i][j] = (f32x16)(0.f);

  bf16x8 a0[2][4], a1[2][4];                 // A halves (single bank each)
  bf16x8 b1r[4];                             // B half 1 (single bank)
  bf16x8 b0r[2][4];                          // B half 0 (double bank)

  // prologue: stage tiles 0 and 1 fully (region order A0,B0,B1,A1 each)
  STG(Ab0,      &lds[0][0][0][0]);
  STG(Bb0,      &lds[1][0][0][0]);
  STG(Bb1,      &lds[1][0][1][0]);
  STG(Ab1,      &lds[0][0][1][0]);
  STG(Ab0 + 64, &lds[0][1][0][0]);
  STG(Bb0 + 64, &lds[1][1][0][0]);
  STG(Bb1 + 64, &lds[1][1][1][0]);
  STG(Ab1 + 64, &lds[0][1][1][0]);
  VM8;                                       // tile0's 8 loads landed
  BAR;
  // pre-read tile0 operands (A1(t0) is read at T0.p0)
  RD_A(a0, 0, 0); RD_B(b0r[0], 0, 0); RD_B(b1r, 0, 1);

  for (int t = 0; t < 32; ++t) {
    const int t2 = 2 * t + 2, t3 = 2 * t + 3;
    const size_t ko2 = (size_t)(t2 < 64 ? t2 : 63) * 64;
    const size_t ko3 = (size_t)(t3 < 64 ? t3 : 63) * 64;
    TILE(0, 1, 0, 1, ko2);                   // even tile 2t
    TILE(1, 0, 1, 0, ko3);                   // odd tile 2t+1
  }
  VM0;                                       // retire trailing (clamped) stages

  // epilogue: route this block's 256 columns to q / k / v region
  size_t obase; int ldc, nc;
  if (n0 < NQ)            { obase = 0;                                        ldc = NQ;  nc = n0; }
  else if (n0 < NQ + NKV) { obase = (size_t)MROWS * NQ;                       ldc = NKV; nc = n0 - NQ; }
  else                    { obase = (size_t)MROWS * NQ + (size_t)MROWS * NKV; ldc = NKV; nc = n0 - NQ - NKV; }

  // C/D layout (verified m74/m101): col = lane&31, row = (reg&3)+8*(reg>>2)+4*hi
#pragma unroll
  for (int I = 0; I < 4; ++I) {
    const int rbase = m0 + (I >> 1) * 128 + wr * 64 + (I & 1) * 32 + hi * 4;
#pragma unroll
    for (int J = 0; J < 2; ++J) {
      const int col = nc + J * 128 + wc * 32 + r32;
#pragma unroll
      for (int reg = 0; reg < 16; ++reg) {
        const int row = rbase + (reg & 3) + 8 * (reg >> 2);
        out[obase + (size_t)row * ldc + col] = acc[I][J][reg];
      }
    }
  }
}

extern "C" void kernel_launch(void* const* d_in, const int* in_sizes, int n_in,
                              void* d_out, int out_size, void* d_ws, size_t ws_size,
                              hipStream_t stream) {
  const float* x     = (const float*)d_in[0];
  const float* gamma = (const float*)d_in[1];
  const float* wq    = (const float*)d_in[2];
  const float* wk    = (const float*)d_in[3];
  const float* wv    = (const float*)d_in[4];
  float* out = (float*)d_out;

  // workspace layout: xn bf16 [8192][4096] then wt bf16 [6144][4096]
  unsigned short* xn = (unsigned short*)d_ws;
  unsigned short* wt = xn + (size_t)MROWS * HD;

  rmsnorm_cast_kernel<<<MROWS, 256, 0, stream>>>(x, gamma, xn);
  transpose_cast_kernel<<<dim3(NQ / 32, HD / 32), 256, 0, stream>>>(wq, wt, NQ);
  transpose_cast_kernel<<<dim3(NKV / 32, HD / 32), 256, 0, stream>>>(
      wk, wt + (size_t)NQ * HD, NKV);
  transpose_cast_kernel<<<dim3(NKV / 32, HD / 32), 256, 0, stream>>>(
      wv, wt + (size_t)(NQ + NKV) * HD, NKV);
  gemm_qkv_kernel<<<(MROWS / 256) * (NTOT / 256), 512, 0, stream>>>(xn, wt, out);
}

// Round 9
// 416.297 us; speedup vs baseline: 3.7602x; 3.7602x over previous
//
#include <hip/hip_runtime.h>
#include <hip/hip_bf16.h>
#include <stdint.h>

// Problem constants (fixed by the reference)
#define HD      4096            // K (hidden)
#define MROWS   8192            // B*S
#define NQ      4096
#define NKV     1024
#define NTOT    6144            // NQ + 2*NKV
#define RMS_EPS 1e-6f

typedef __attribute__((ext_vector_type(8))) short bf16x8;
typedef __attribute__((ext_vector_type(16))) float f32x16;

static __device__ __forceinline__ unsigned short f2bf(float f) {
  union { float f; unsigned u; } a; a.f = f;
  unsigned r = a.u + 0x7FFFu + ((a.u >> 16) & 1u);   // RNE
  return (unsigned short)(r >> 16);
}

// ---------------- RMSNorm + cast to bf16 ----------------
__global__ __launch_bounds__(256) void rmsnorm_cast_kernel(
    const float* __restrict__ x, const float* __restrict__ gamma,
    unsigned short* __restrict__ xn) {
  const int row = blockIdx.x;                 // 8192 rows
  const float4* xr = (const float4*)(x + (size_t)row * HD);
  const float4* g4 = (const float4*)gamma;
  const int t = threadIdx.x;                  // 256 threads
  float4 v[4];
  float ss = 0.f;
#pragma unroll
  for (int i = 0; i < 4; ++i) {
    v[i] = xr[t + i * 256];
    ss += v[i].x * v[i].x + v[i].y * v[i].y + v[i].z * v[i].z + v[i].w * v[i].w;
  }
#pragma unroll
  for (int o = 32; o > 0; o >>= 1) ss += __shfl_xor(ss, o, 64);
  __shared__ float red[4];
  if ((t & 63) == 0) red[t >> 6] = ss;
  __syncthreads();
  const float tot = red[0] + red[1] + red[2] + red[3];
  const float rstd = rsqrtf(tot * (1.f / HD) + RMS_EPS);
  ushort4* xo = (ushort4*)(xn + (size_t)row * HD);
#pragma unroll
  for (int i = 0; i < 4; ++i) {
    const float4 g = g4[t + i * 256];
    ushort4 o;
    o.x = f2bf(v[i].x * rstd * g.x);
    o.y = f2bf(v[i].y * rstd * g.y);
    o.z = f2bf(v[i].z * rstd * g.z);
    o.w = f2bf(v[i].w * rstd * g.w);
    xo[t + i * 256] = o;
  }
}

// ---------------- Transpose + cast W[K][Nw] f32 -> Wt[Nw][K] bf16 ----------------
__global__ __launch_bounds__(256) void transpose_cast_kernel(
    const float* __restrict__ w, unsigned short* __restrict__ wt, int Nw) {
  __shared__ float tile[32][33];
  const int kt = blockIdx.y;                  // K/32
  const int nb = blockIdx.x;                  // Nw/32
  const int t = threadIdx.x;
  const int r = t >> 3, c4 = t & 7;
  const float4 vin = *(const float4*)&w[(size_t)(kt * 32 + r) * Nw + nb * 32 + c4 * 4];
  tile[r][c4 * 4 + 0] = vin.x;
  tile[r][c4 * 4 + 1] = vin.y;
  tile[r][c4 * 4 + 2] = vin.z;
  tile[r][c4 * 4 + 3] = vin.w;
  __syncthreads();
  ushort4 o;
  o.x = f2bf(tile[c4 * 4 + 0][r]);
  o.y = f2bf(tile[c4 * 4 + 1][r]);
  o.z = f2bf(tile[c4 * 4 + 2][r]);
  o.w = f2bf(tile[c4 * 4 + 3][r]);
  *(ushort4*)&wt[(size_t)(nb * 32 + r) * HD + kt * 32 + c4 * 4] = o;
}

// ---- 256x256 lookahead-read bf16 GEMM, 32x32x16, 8 phases x 4 MFMA ----
// C[M,N] = A[M,K] * Bt[N,K]^T ; M=8192, N=6144, K=4096. BK=64, 512 thr.
//
// Phase (HA, kh, HB); every operand read 1-3 phases BEFORE its consuming
// MFMA so the lgkm wait is serviced under the previous phase's MFMA.
// Frags: aP/aN ping-pong (4 b128 each), B held 4 frags (8 b128) read-once.
// 64 frag VGPR + acc 128 (AGPR) -> arch target <=128 (2 waves/SIMD).
//
// Read schedule (per tile T, buf c, next n):   use ->
//   p0: B(c,HB1,kh1)->b[1][1]                  p3,p7
//   p1: A(c,HA0,kh1)->aN                       p2,p3
//   p3: A(c,HA1,kh0)->aP                       p4,p5
//   p5: A(c,HA1,kh1)->aN ; B(n,HB0,kh0)->b[0][0]   p6,p7 ; T+1.p0,p4
//   p6: A(n,HA0,kh0)->aP                       T+1.p0,p1
//   p7: B(n,HB1,kh0)->b[1][0]; B(n,HB0,kh1)->b[0][1]  T+1.p1,p5 ; T+1.p2,p6
// Stage schedule (tile T+2 -> buf c, >=2 phases after region's last read):
//   p1: c.B0  p2: c.B1  p3: c.A0  p7: c.A1   (2 gload_lds each)
// VM ledger (simulated fixed point; queue entering p0 = 10):
//   VM10@p2 (pre-stage): retires T-2.A1  -> p3's A(c,HA1,kh0) read safe
//   VM12@p4:             retires T-1.B0  -> p5's B(n,HB0,kh0) read safe
//   VM8@p5:              retires T-1.B1, T-1.A0 -> p6/p7 n-reads safe
//   Never vmcnt(0) in the loop; VM8 after 16-load prologue; clamped-KO tail
//   keeps the ledger uniform (dup loads harmless, dead reads unused).

static __device__ __forceinline__ void gload_lds16(const unsigned short* g,
                                                   unsigned short* l) {
  __builtin_amdgcn_global_load_lds(
      (const __attribute__((address_space(1))) void*)g,
      (__attribute__((address_space(3))) void*)l, 16, 0, 0);
}

#define VM12 asm volatile("s_waitcnt vmcnt(12)" ::: "memory")
#define VM10 asm volatile("s_waitcnt vmcnt(10)" ::: "memory")
#define VM8  asm volatile("s_waitcnt vmcnt(8)" ::: "memory")
#define VM0  asm volatile("s_waitcnt vmcnt(0)" ::: "memory")
#define BAR  __builtin_amdgcn_s_barrier()

// byte slot for logical k-step ks (0..3): ((ks*2+hi)^swx)<<4
#define SLOT(ks) ((((ks) * 2 + hi) ^ swx) << 4)

// read 4 A frags (mi x k within kh) of (BUF, HA, KH) into DST[2][2]
#define RDA(DST, BUF, HA, KH)                                                  \
  do {                                                                         \
    const char* Ah = (const char*)&lds[0][BUF][HA][0];                         \
    _Pragma("unroll") for (int mi = 0; mi < 2; ++mi)                           \
      _Pragma("unroll") for (int k = 0; k < 2; ++k)                            \
        DST[mi][k] = *(const bf16x8*)(Ah + arow + mi * 4096 +                  \
                                      SLOT((KH) * 2 + k));                     \
  } while (0)

// read 2 B frags (k within kh) of (BUF, HB, KH) into b[HB][KH][*]
#define RDB(HB, BUF, KH)                                                       \
  do {                                                                         \
    const char* Bh = (const char*)&lds[1][BUF][HB][0];                         \
    _Pragma("unroll") for (int k = 0; k < 2; ++k)                              \
      b[HB][KH][k] = *(const bf16x8*)(Bh + brow + SLOT((KH) * 2 + k));         \
  } while (0)

// 4 MFMA for quadrant (HA, HB) k-half KH using A regs AR
#define MM4(HA, HB, KH, AR)                                                    \
  do {                                                                         \
    __builtin_amdgcn_s_setprio(1);                                             \
    _Pragma("unroll") for (int k = 0; k < 2; ++k)                              \
      _Pragma("unroll") for (int mi = 0; mi < 2; ++mi)                         \
        acc[(HA) * 2 + mi][HB] = __builtin_amdgcn_mfma_f32_32x32x16_bf16(      \
            AR[mi][k], b[HB][KH][k], acc[(HA) * 2 + mi][HB], 0, 0, 0);         \
    __builtin_amdgcn_s_setprio(0);                                             \
  } while (0)

// One K-tile (8 phases). BUF = this tile's buf, NBUF = next tile's buf,
// KO = element k-offset of tile T+2 (clamped at the tail).
#define TILE(BUF, NBUF, KO)                                                    \
  do {                                                                         \
    /* p0 */ RDB(1, BUF, 1);                                                   \
    BAR; MM4(0, 0, 0, aP);                                                     \
    /* p1 */ RDA(aN, BUF, 0, 1); STG(Bb0 + (KO), &lds[1][BUF][0][0]);          \
    BAR; MM4(0, 1, 0, aP);                                                     \
    /* p2 */ VM10; STG(Bb1 + (KO), &lds[1][BUF][1][0]);                        \
    BAR; MM4(0, 0, 1, aN);                                                     \
    /* p3 */ RDA(aP, BUF, 1, 0); STG(Ab0 + (KO), &lds[0][BUF][0][0]);          \
    BAR; MM4(0, 1, 1, aN);                                                     \
    /* p4 */ VM12;                                                             \
    BAR; MM4(1, 0, 0, aP);                                                     \
    /* p5 */ RDA(aN, BUF, 1, 1); RDB(0, NBUF, 0); VM8;                         \
    BAR; MM4(1, 1, 0, aP);                                                     \
    /* p6 */ RDA(aP, NBUF, 0, 0);                                              \
    BAR; MM4(1, 0, 1, aN);                                                     \
    /* p7 */ RDB(1, NBUF, 0); RDB(0, NBUF, 1);                                 \
    STG(Ab1 + (KO), &lds[0][BUF][1][0]);                                       \
    BAR; MM4(1, 1, 1, aN);                                                     \
  } while (0)

__global__ __launch_bounds__(512, 2) void gemm_qkv_kernel(
    const unsigned short* __restrict__ A,    // [MROWS][HD] bf16 (xn)
    const unsigned short* __restrict__ Bt,   // [NTOT][HD] bf16 (w^T)
    float* __restrict__ out) {
  // [mat A/B][buf][row-half][128 rows x 64 k] bf16 = 128 KiB total
  __shared__ unsigned short lds[2][2][2][8192] __attribute__((aligned(16)));

  // XCD-rectangular swizzle: grid 32mt x 24nt = 768 blocks, XCD = bid&7.
  const int bid = blockIdx.x;
  const int xcd = bid & 7;
  const int idx = bid >> 3;                  // 0..95
  const int sr  = idx >> 5;                  // sub-round 0..2
  const int i32 = idx & 31;
  const int mt  = (xcd >> 1) * 8 + (i32 >> 2);
  const int nt  = (xcd & 1) * 12 + sr * 4 + (i32 & 3);
  const int m0 = mt * 256, n0 = nt * 256;

  const int tid = threadIdx.x;
  const int w = tid >> 6, lane = tid & 63;
  const int wr = w >> 2, wc = w & 3;         // 2 x 4 waves, each 128x64 out
  const int r32 = lane & 31, hi = lane >> 5; // 32x32 fragment coords
  const int swx = (r32 >> 1) & 7;            // bank swizzle field
  const int arow = (wr * 64 + r32) * 128;    // per-lane A row byte offset
  const int brow = (wc * 32 + r32) * 128;    // per-lane B row byte offset

  // staging: linear LDS dest, inverse-swizzled global source (rule #21)
  const int wslot = w * 512;                 // wave-uniform LDS element base
  const int r3 = tid >> 3;                   // row 0..63 within pass
  const unsigned scol = (unsigned)(((tid & 7) ^ ((r3 >> 1) & 7)) << 3);
  const unsigned so0 = (unsigned)r3 * HD + scol;
  const unsigned so1 = so0 + 64u * HD;

  const unsigned short* const Ab0 = A + (size_t)m0 * HD;
  const unsigned short* const Ab1 = Ab0 + (size_t)128 * HD;
  const unsigned short* const Bb0 = Bt + (size_t)n0 * HD;
  const unsigned short* const Bb1 = Bb0 + (size_t)128 * HD;

  auto STG = [&](const unsigned short* g, unsigned short* l) {
    gload_lds16(g + so0, l + wslot);
    gload_lds16(g + so1, l + 4096 + wslot);
  };

  f32x16 acc[4][2];
#pragma unroll
  for (int i = 0; i < 4; ++i)
#pragma unroll
    for (int j = 0; j < 2; ++j) acc[i][j] = (f32x16)(0.f);

  bf16x8 aP[2][2], aN[2][2];                 // A ping-pong [mi][k]
  bf16x8 b[2][2][2];                         // B held [HB][KH][k]

  // prologue: stage tile0 -> buf0, tile1 -> buf1 (order B0,B1,A0,A1 each)
  STG(Bb0,      &lds[1][0][0][0]);
  STG(Bb1,      &lds[1][0][1][0]);
  STG(Ab0,      &lds[0][0][0][0]);
  STG(Ab1,      &lds[0][0][1][0]);
  STG(Bb0 + 64, &lds[1][1][0][0]);
  STG(Bb1 + 64, &lds[1][1][1][0]);
  STG(Ab0 + 64, &lds[0][1][0][0]);
  STG(Ab1 + 64, &lds[0][1][1][0]);
  VM8;                                       // tile0's 8 loads retired
  BAR;
  // pre-reads matching steady entry state of p0
  RDA(aP, 0, 0, 0);                          // A(c,HA0,kh0)
  RDB(0, 0, 0);                              // B(c,HB0,kh0)
  RDB(1, 0, 0);                              // B(c,HB1,kh0)
  RDB(0, 0, 1);                              // B(c,HB0,kh1)

  for (int t = 0; t < 32; ++t) {
    const int t2 = 2 * t + 2, t3 = 2 * t + 3;
    const int ko2 = (t2 < 64 ? t2 : 63) * 64;
    const int ko3 = (t3 < 64 ? t3 : 63) * 64;
    TILE(0, 1, ko2);                         // even tile 2t
    TILE(1, 0, ko3);                         // odd tile 2t+1
  }
  VM0;                                       // retire trailing clamped stages

  // epilogue: route this block's 256 columns to q / k / v region
  size_t obase; int ldc, nc;
  if (n0 < NQ)            { obase = 0;                                        ldc = NQ;  nc = n0; }
  else if (n0 < NQ + NKV) { obase = (size_t)MROWS * NQ;                       ldc = NKV; nc = n0 - NQ; }
  else                    { obase = (size_t)MROWS * NQ + (size_t)MROWS * NKV; ldc = NKV; nc = n0 - NQ - NKV; }

  // C/D layout (verified m74/m101): col = lane&31, row = (reg&3)+8*(reg>>2)+4*hi
#pragma unroll
  for (int I = 0; I < 4; ++I) {
    const int rbase = m0 + (I >> 1) * 128 + wr * 64 + (I & 1) * 32 + hi * 4;
#pragma unroll
    for (int J = 0; J < 2; ++J) {
      const int col = nc + J * 128 + wc * 32 + r32;
#pragma unroll
      for (int reg = 0; reg < 16; ++reg) {
        const int row = rbase + (reg & 3) + 8 * (reg >> 2);
        out[obase + (size_t)row * ldc + col] = acc[I][J][reg];
      }
    }
  }
}

extern "C" void kernel_launch(void* const* d_in, const int* in_sizes, int n_in,
                              void* d_out, int out_size, void* d_ws, size_t ws_size,
                              hipStream_t stream) {
  const float* x     = (const float*)d_in[0];
  const float* gamma = (const float*)d_in[1];
  const float* wq    = (const float*)d_in[2];
  const float* wk    = (const float*)d_in[3];
  const float* wv    = (const float*)d_in[4];
  float* out = (float*)d_out;

  // workspace layout: xn bf16 [8192][4096] then wt bf16 [6144][4096]
  unsigned short* xn = (unsigned short*)d_ws;
  unsigned short* wt = xn + (size_t)MROWS * HD;

  rmsnorm_cast_kernel<<<MROWS, 256, 0, stream>>>(x, gamma, xn);
  transpose_cast_kernel<<<dim3(NQ / 32, HD / 32), 256, 0, stream>>>(wq, wt, NQ);
  transpose_cast_kernel<<<dim3(NKV / 32, HD / 32), 256, 0, stream>>>(
      wk, wt + (size_t)NQ * HD, NKV);
  transpose_cast_kernel<<<dim3(NKV / 32, HD / 32), 256, 0, stream>>>(
      wv, wt + (size_t)(NQ + NKV) * HD, NKV);
  gemm_qkv_kernel<<<(MROWS / 256) * (NTOT / 256), 512, 0, stream>>>(xn, wt, out);
}